// Round 3
// baseline (372.640 us; speedup 1.0000x reference)
//
#include <hip/hip_runtime.h>

#define CDIV(a,b) (((a)+(b)-1)/(b))

// ---------------- zero int buffer (graph-capture-safe memset) ----------------
__global__ void zero_kernel(int* __restrict__ p, int n) {
    int i = blockIdx.x * blockDim.x + threadIdx.x;
    if (i < n) p[i] = 0;
}

// ---------------- degree histogram ----------------
__global__ void hist_kernel(const int* __restrict__ coli, int* __restrict__ counts, int E) {
    int e = blockIdx.x * blockDim.x + threadIdx.x;
    if (e < E) atomicAdd(&counts[coli[e]], 1);
}

// ---------------- single-block exclusive scan + dinv ----------------
__global__ void scan_kernel(const int* __restrict__ counts, int* __restrict__ offsets,
                            int* __restrict__ nexta, float* __restrict__ dinv, int n) {
    __shared__ int wsum[16];
    __shared__ int s_carry, s_tot;
    int tid  = threadIdx.x;
    int lane = tid & 63, wid = tid >> 6;
    if (tid == 0) { s_carry = 0; offsets[0] = 0; }
    __syncthreads();
    for (int base = 0; base < n; base += 1024) {
        int i = base + tid;
        int v = (i < n) ? counts[i] : 0;
        if (i < n) dinv[i] = 1.0f / sqrtf((float)(v + 1));  // self-loop => deg >= 1
        // wave-inclusive scan
        int x = v;
        #pragma unroll
        for (int off = 1; off < 64; off <<= 1) {
            int t = __shfl_up(x, off);
            if (lane >= off) x += t;
        }
        if (lane == 63) wsum[wid] = x;
        __syncthreads();
        if (tid == 0) {
            int run = 0;
            #pragma unroll
            for (int w = 0; w < 16; ++w) { int t = wsum[w]; wsum[w] = run; run += t; }
            s_tot = run;
        }
        __syncthreads();
        int carry = s_carry;
        int incl  = carry + wsum[wid] + x;     // inclusive prefix including this element
        if (i < n) { offsets[i + 1] = incl; nexta[i] = incl - v; }
        __syncthreads();
        if (tid == 0) s_carry = carry + s_tot;
        __syncthreads();
    }
}

// ---------------- counting-sort scatter (build CSR src lists) ----------------
__global__ void scatter_kernel(const int* __restrict__ rowi, const int* __restrict__ coli,
                               int* __restrict__ nexta, int* __restrict__ srcs, int E) {
    int e = blockIdx.x * blockDim.x + threadIdx.x;
    if (e < E) {
        int c = coli[e];
        int pos = atomicAdd(&nexta[c], 1);
        srcs[pos] = rowi[e];
    }
}

// ---------------- aggregation, 1 wave per destination, float4 lanes (256 ch) ----------------
// 4x edge unroll: 4 independent row-gathers in flight per wave.
__global__ void agg_kernel_f4(const float* __restrict__ xin, const int* __restrict__ srcs,
                              const int* __restrict__ offsets, const float* __restrict__ dinv,
                              float* __restrict__ xout, float* __restrict__ sarr,
                              int vpr, int n) {
    int gw   = blockIdx.x * (blockDim.x >> 6) + (threadIdx.x >> 6);
    int lane = threadIdx.x & 63;
    if (gw >= n || lane >= vpr) return;
    int c   = __builtin_amdgcn_readfirstlane(gw);     // wave-uniform dest node
    int beg = __builtin_amdgcn_readfirstlane(offsets[c]);
    int end = __builtin_amdgcn_readfirstlane(offsets[c + 1]);
    const float4* x4 = (const float4*)xin;
    float4 acc = make_float4(0.f, 0.f, 0.f, 0.f);
    float wsum = 0.f;
    int i = beg;
    for (; i + 3 < end; i += 4) {
        int r0 = __builtin_amdgcn_readfirstlane(srcs[i + 0]);
        int r1 = __builtin_amdgcn_readfirstlane(srcs[i + 1]);
        int r2 = __builtin_amdgcn_readfirstlane(srcs[i + 2]);
        int r3 = __builtin_amdgcn_readfirstlane(srcs[i + 3]);
        float w0 = dinv[r0], w1 = dinv[r1], w2 = dinv[r2], w3 = dinv[r3];
        float4 v0 = x4[(size_t)r0 * vpr + lane];
        float4 v1 = x4[(size_t)r1 * vpr + lane];
        float4 v2 = x4[(size_t)r2 * vpr + lane];
        float4 v3 = x4[(size_t)r3 * vpr + lane];
        acc.x = fmaf(w0, v0.x, acc.x); acc.y = fmaf(w0, v0.y, acc.y);
        acc.z = fmaf(w0, v0.z, acc.z); acc.w = fmaf(w0, v0.w, acc.w);
        acc.x = fmaf(w1, v1.x, acc.x); acc.y = fmaf(w1, v1.y, acc.y);
        acc.z = fmaf(w1, v1.z, acc.z); acc.w = fmaf(w1, v1.w, acc.w);
        acc.x = fmaf(w2, v2.x, acc.x); acc.y = fmaf(w2, v2.y, acc.y);
        acc.z = fmaf(w2, v2.z, acc.z); acc.w = fmaf(w2, v2.w, acc.w);
        acc.x = fmaf(w3, v3.x, acc.x); acc.y = fmaf(w3, v3.y, acc.y);
        acc.z = fmaf(w3, v3.z, acc.z); acc.w = fmaf(w3, v3.w, acc.w);
        wsum += w0 + w1 + w2 + w3;
    }
    for (; i < end; ++i) {
        int r   = __builtin_amdgcn_readfirstlane(srcs[i]);
        float w = dinv[r];
        float4 v = x4[(size_t)r * vpr + lane];
        acc.x = fmaf(w, v.x, acc.x);
        acc.y = fmaf(w, v.y, acc.y);
        acc.z = fmaf(w, v.z, acc.z);
        acc.w = fmaf(w, v.w, acc.w);
        wsum += w;
    }
    float dc = dinv[c];
    float4 vc = x4[(size_t)c * vpr + lane];
    acc.x = fmaf(dc, vc.x, acc.x);
    acc.y = fmaf(dc, vc.y, acc.y);
    acc.z = fmaf(dc, vc.z, acc.z);
    acc.w = fmaf(dc, vc.w, acc.w);
    wsum += dc;
    acc.x *= dc; acc.y *= dc; acc.z *= dc; acc.w *= dc;
    ((float4*)xout)[(size_t)c * vpr + lane] = acc;
    if (sarr && lane == 0) sarr[c] = dc * wsum;   // s = rowsum of A_norm (for bias aggregation)
}

// ---------------- aggregation, float2 lanes (128 ch), 4x edge unroll ----------------
__global__ void agg_kernel_f2(const float* __restrict__ xin, const int* __restrict__ srcs,
                              const int* __restrict__ offsets, const float* __restrict__ dinv,
                              float* __restrict__ xout, int vpr, int n) {
    int gw   = blockIdx.x * (blockDim.x >> 6) + (threadIdx.x >> 6);
    int lane = threadIdx.x & 63;
    if (gw >= n || lane >= vpr) return;
    int c   = __builtin_amdgcn_readfirstlane(gw);
    int beg = __builtin_amdgcn_readfirstlane(offsets[c]);
    int end = __builtin_amdgcn_readfirstlane(offsets[c + 1]);
    const float2* x2 = (const float2*)xin;
    float2 acc = make_float2(0.f, 0.f);
    int i = beg;
    for (; i + 3 < end; i += 4) {
        int r0 = __builtin_amdgcn_readfirstlane(srcs[i + 0]);
        int r1 = __builtin_amdgcn_readfirstlane(srcs[i + 1]);
        int r2 = __builtin_amdgcn_readfirstlane(srcs[i + 2]);
        int r3 = __builtin_amdgcn_readfirstlane(srcs[i + 3]);
        float w0 = dinv[r0], w1 = dinv[r1], w2 = dinv[r2], w3 = dinv[r3];
        float2 v0 = x2[(size_t)r0 * vpr + lane];
        float2 v1 = x2[(size_t)r1 * vpr + lane];
        float2 v2 = x2[(size_t)r2 * vpr + lane];
        float2 v3 = x2[(size_t)r3 * vpr + lane];
        acc.x = fmaf(w0, v0.x, acc.x); acc.y = fmaf(w0, v0.y, acc.y);
        acc.x = fmaf(w1, v1.x, acc.x); acc.y = fmaf(w1, v1.y, acc.y);
        acc.x = fmaf(w2, v2.x, acc.x); acc.y = fmaf(w2, v2.y, acc.y);
        acc.x = fmaf(w3, v3.x, acc.x); acc.y = fmaf(w3, v3.y, acc.y);
    }
    for (; i < end; ++i) {
        int r   = __builtin_amdgcn_readfirstlane(srcs[i]);
        float w = dinv[r];
        float2 v = x2[(size_t)r * vpr + lane];
        acc.x = fmaf(w, v.x, acc.x);
        acc.y = fmaf(w, v.y, acc.y);
    }
    float dc = dinv[c];
    float2 vc = x2[(size_t)c * vpr + lane];
    acc.x = fmaf(dc, vc.x, acc.x);
    acc.y = fmaf(dc, vc.y, acc.y);
    acc.x *= dc; acc.y *= dc;
    ((float2*)xout)[(size_t)c * vpr + lane] = acc;
}

// ---------------- fp32 tiled GEMM: C = A@B + bias (optionally s[row]*bias), opt ReLU ----------------
// 256 threads as 16x16, micro-tile TM x TN. BK fixed at 16.
template<int BM, int BN, bool RELU, bool SBIAS>
__global__ __launch_bounds__(256) void gemm_kernel(
        const float* __restrict__ A, const float* __restrict__ B,
        const float* __restrict__ bias, const float* __restrict__ sarr,
        float* __restrict__ C, int M, int K, int N) {
    constexpr int BK = 16;
    constexpr int TM = BM / 16, TN = BN / 16;
    static_assert(BM % 16 == 0 && BN % 16 == 0, "tile");
    __shared__ float As[BK][BM + 4];   // transposed: As[k][m]
    __shared__ float Bs[BK][BN + 4];
    int tid = threadIdx.x;
    int ty = tid >> 4, tx = tid & 15;
    int m0 = blockIdx.x * BM, n0 = blockIdx.y * BN;
    float acc[TM][TN] = {};
    for (int k0 = 0; k0 < K; k0 += BK) {
        // A tile: BM x 16, float4 along K, store transposed
        #pragma unroll
        for (int l = 0; l < BM * BK / 1024; ++l) {
            int idx = tid + l * 256;
            int m  = idx >> 2;       // 4 float4 per row (BK=16)
            int kq = idx & 3;
            int gm = m0 + m;
            float4 v = make_float4(0.f, 0.f, 0.f, 0.f);
            if (gm < M) v = *(const float4*)(A + (size_t)gm * K + k0 + kq * 4);
            As[kq * 4 + 0][m] = v.x;
            As[kq * 4 + 1][m] = v.y;
            As[kq * 4 + 2][m] = v.z;
            As[kq * 4 + 3][m] = v.w;
        }
        // B tile: 16 x BN, float4 along N
        #pragma unroll
        for (int l = 0; l < BK * BN / 1024; ++l) {
            int idx = tid + l * 256;
            int kk = idx / (BN / 4);
            int nq = idx % (BN / 4);
            float4 v = *(const float4*)(B + (size_t)(k0 + kk) * N + n0 + nq * 4);
            *(float4*)(&Bs[kk][nq * 4]) = v;
        }
        __syncthreads();
        #pragma unroll
        for (int kk = 0; kk < BK; ++kk) {
            float a[TM], b[TN];
            #pragma unroll
            for (int i = 0; i < TM; ++i) a[i] = As[kk][ty * TM + i];
            #pragma unroll
            for (int j = 0; j < TN; ++j) b[j] = Bs[kk][tx * TN + j];
            #pragma unroll
            for (int i = 0; i < TM; ++i)
                #pragma unroll
                for (int j = 0; j < TN; ++j)
                    acc[i][j] = fmaf(a[i], b[j], acc[i][j]);
        }
        __syncthreads();
    }
    #pragma unroll
    for (int i = 0; i < TM; ++i) {
        int row = m0 + ty * TM + i;
        if (row >= M) continue;
        float sv = SBIAS ? sarr[row] : 0.f;
        #pragma unroll
        for (int j = 0; j < TN; ++j) {
            int colj = n0 + tx * TN + j;
            float v = acc[i][j] + (SBIAS ? sv * bias[colj] : bias[colj]);
            if (RELU) v = fmaxf(v, 0.f);
            C[(size_t)row * N + colj] = v;
        }
    }
}

extern "C" void kernel_launch(void* const* d_in, const int* in_sizes, int n_in,
                              void* d_out, int out_size, void* d_ws, size_t ws_size,
                              hipStream_t stream) {
    const float* x  = (const float*)d_in[0];
    const int*   ei = (const int*)d_in[1];
    const float* W1 = (const float*)d_in[2];
    const float* b1 = (const float*)d_in[3];
    const float* W2 = (const float*)d_in[4];
    const float* b2 = (const float*)d_in[5];

    const int hid  = in_sizes[3];             // 512
    const int outc = in_sizes[5];             // 128
    const int inc  = in_sizes[2] / hid;       // 256
    const int n    = in_sizes[0] / inc;       // 20000
    const int E    = in_sizes[1] / 2;         // 640000
    const int* rowi = ei;                     // edge_index[0] = sources
    const int* coli = ei + E;                 // edge_index[1] = destinations

    char* p = (char*)d_ws;
    auto carve = [&](size_t bytes) {
        char* q = p;
        p += (bytes + 255) & ~(size_t)255;
        return (void*)q;
    };
    int*   counts  = (int*)  carve((size_t)n * 4);
    int*   offsets = (int*)  carve((size_t)(n + 1) * 4);
    int*   nexta   = (int*)  carve((size_t)n * 4);
    int*   srcs    = (int*)  carve((size_t)E * 4);
    float* dinv    = (float*)carve((size_t)n * 4);
    float* sarr    = (float*)carve((size_t)n * 4);
    float* aggx    = (float*)carve((size_t)n * inc * 4);   // also reused as z (n*outc <= n*inc)
    float* h       = (float*)carve((size_t)n * hid * 4);
    float* z       = aggx;                                  // alias: aggx dead after GEMM1

    zero_kernel<<<CDIV(n, 256), 256, 0, stream>>>(counts, n);
    hist_kernel<<<CDIV(E, 256), 256, 0, stream>>>(coli, counts, E);
    scan_kernel<<<1, 1024, 0, stream>>>(counts, offsets, nexta, dinv, n);
    scatter_kernel<<<CDIV(E, 256), 256, 0, stream>>>(rowi, coli, nexta, srcs, E);

    // layer 1: aggregate-then-GEMM:  h = relu((A@x) @ W1 + s*b1)
    agg_kernel_f4<<<CDIV(n, 4), 256, 0, stream>>>(x, srcs, offsets, dinv, aggx, sarr, inc / 4, n);
    dim3 g1(CDIV(n, 128), hid / 128);
    gemm_kernel<128, 128, true, true><<<g1, 256, 0, stream>>>(aggx, W1, b1, sarr, h, n, inc, hid);

    // layer 2: GEMM-then-aggregate:  out = A@(h @ W2 + b2)
    dim3 g2(CDIV(n, 64), outc / 128);
    gemm_kernel<64, 128, false, false><<<g2, 256, 0, stream>>>(h, W2, b2, nullptr, z, n, hid, outc);
    agg_kernel_f2<<<CDIV(n, 4), 256, 0, stream>>>(z, srcs, offsets, dinv, (float*)d_out, outc / 2, n);
}

// Round 4
// 298.944 us; speedup vs baseline: 1.2465x; 1.2465x over previous
//
#include <hip/hip_runtime.h>

#define CDIV(a,b) (((a)+(b)-1)/(b))

typedef _Float16 half4v __attribute__((ext_vector_type(4)));
typedef _Float16 half2v __attribute__((ext_vector_type(2)));

// ---------------- zero int buffer (graph-capture-safe memset) ----------------
__global__ void zero_kernel(int* __restrict__ p, int n) {
    int i = blockIdx.x * blockDim.x + threadIdx.x;
    if (i < n) p[i] = 0;
}

// ---------------- degree histogram ----------------
__global__ void hist_kernel(const int* __restrict__ coli, int* __restrict__ counts, int E) {
    int e = blockIdx.x * blockDim.x + threadIdx.x;
    if (e < E) atomicAdd(&counts[coli[e]], 1);
}

// ---------------- hierarchical scan: part 1 (block-local inclusive) ----------------
__global__ __launch_bounds__(1024) void scan_part(const int* __restrict__ counts,
                                                  int* __restrict__ offsets,
                                                  int* __restrict__ bsum,
                                                  float* __restrict__ dinv, int n) {
    __shared__ int wsum[16];
    int b = blockIdx.x, tid = threadIdx.x;
    int i = b * 1024 + tid;
    int lane = tid & 63, wid = tid >> 6;
    int v = (i < n) ? counts[i] : 0;
    if (i < n) dinv[i] = 1.0f / sqrtf((float)(v + 1));   // self-loop => deg >= 1
    int x = v;
    #pragma unroll
    for (int off = 1; off < 64; off <<= 1) {
        int t = __shfl_up(x, off);
        if (lane >= off) x += t;
    }
    if (lane == 63) wsum[wid] = x;
    __syncthreads();
    if (tid == 0) {
        int run = 0;
        #pragma unroll
        for (int w = 0; w < 16; ++w) { int t = wsum[w]; wsum[w] = run; run += t; }
        bsum[b] = run;
    }
    __syncthreads();
    int incl = wsum[wid] + x;           // block-local inclusive prefix
    if (i < n) offsets[i + 1] = incl;
}

// ---------------- hierarchical scan: part 2 (add block prefix, emit nexta) ----------------
__global__ __launch_bounds__(1024) void scan_fix(const int* __restrict__ counts,
                                                 int* __restrict__ offsets,
                                                 const int* __restrict__ bsum,
                                                 int* __restrict__ nexta, int n) {
    int b = blockIdx.x, tid = threadIdx.x;
    int i = b * 1024 + tid;
    int pre = 0;
    for (int j = 0; j < b; ++j) pre += bsum[j];   // <=19 uniform loads
    if (i == 0) offsets[0] = 0;
    if (i < n) {
        int incl = offsets[i + 1] + pre;
        offsets[i + 1] = incl;
        nexta[i] = incl - counts[i];              // exclusive prefix = scatter cursor
    }
}

// ---------------- counting-sort scatter (build CSR src lists) ----------------
__global__ void scatter_kernel(const int* __restrict__ rowi, const int* __restrict__ coli,
                               int* __restrict__ nexta, int* __restrict__ srcs, int E) {
    int e = blockIdx.x * blockDim.x + threadIdx.x;
    if (e < E) {
        int c = coli[e];
        int pos = atomicAdd(&nexta[c], 1);
        srcs[pos] = rowi[e];
    }
}

// ---------------- fp32 -> fp16 table conversion ----------------
__global__ void tohalf_kernel(const float* __restrict__ in, _Float16* __restrict__ out, int n4) {
    int i = blockIdx.x * blockDim.x + threadIdx.x;
    if (i < n4) {
        float4 v = ((const float4*)in)[i];
        half4v h;
        h.x = (_Float16)v.x; h.y = (_Float16)v.y;
        h.z = (_Float16)v.z; h.w = (_Float16)v.w;
        ((half4v*)out)[i] = h;
    }
}

// ---------------- layer-1 aggregation: fp16 gather (256 ch), fp32 accum ----------------
// 1 wave per destination, lane = half4 (8 B), 4x edge unroll.
__global__ void agg1_f16(const _Float16* __restrict__ xh, const int* __restrict__ srcs,
                         const int* __restrict__ offsets, const float* __restrict__ dinv,
                         float* __restrict__ xout, float* __restrict__ sarr,
                         int vpr, int n) {
    int gw   = blockIdx.x * (blockDim.x >> 6) + (threadIdx.x >> 6);
    int lane = threadIdx.x & 63;
    if (gw >= n) return;
    int c   = __builtin_amdgcn_readfirstlane(gw);
    int beg = __builtin_amdgcn_readfirstlane(offsets[c]);
    int end = __builtin_amdgcn_readfirstlane(offsets[c + 1]);
    const half4v* x4 = (const half4v*)xh;
    float4 acc = make_float4(0.f, 0.f, 0.f, 0.f);
    float wsum = 0.f;
    int i = beg;
    for (; i + 3 < end; i += 4) {
        int r0 = __builtin_amdgcn_readfirstlane(srcs[i + 0]);
        int r1 = __builtin_amdgcn_readfirstlane(srcs[i + 1]);
        int r2 = __builtin_amdgcn_readfirstlane(srcs[i + 2]);
        int r3 = __builtin_amdgcn_readfirstlane(srcs[i + 3]);
        float w0 = dinv[r0], w1 = dinv[r1], w2 = dinv[r2], w3 = dinv[r3];
        half4v v0 = x4[(size_t)r0 * vpr + lane];
        half4v v1 = x4[(size_t)r1 * vpr + lane];
        half4v v2 = x4[(size_t)r2 * vpr + lane];
        half4v v3 = x4[(size_t)r3 * vpr + lane];
        acc.x = fmaf(w0, (float)v0.x, acc.x); acc.y = fmaf(w0, (float)v0.y, acc.y);
        acc.z = fmaf(w0, (float)v0.z, acc.z); acc.w = fmaf(w0, (float)v0.w, acc.w);
        acc.x = fmaf(w1, (float)v1.x, acc.x); acc.y = fmaf(w1, (float)v1.y, acc.y);
        acc.z = fmaf(w1, (float)v1.z, acc.z); acc.w = fmaf(w1, (float)v1.w, acc.w);
        acc.x = fmaf(w2, (float)v2.x, acc.x); acc.y = fmaf(w2, (float)v2.y, acc.y);
        acc.z = fmaf(w2, (float)v2.z, acc.z); acc.w = fmaf(w2, (float)v2.w, acc.w);
        acc.x = fmaf(w3, (float)v3.x, acc.x); acc.y = fmaf(w3, (float)v3.y, acc.y);
        acc.z = fmaf(w3, (float)v3.z, acc.z); acc.w = fmaf(w3, (float)v3.w, acc.w);
        wsum += w0 + w1 + w2 + w3;
    }
    for (; i < end; ++i) {
        int r   = __builtin_amdgcn_readfirstlane(srcs[i]);
        float w = dinv[r];
        half4v v = x4[(size_t)r * vpr + lane];
        acc.x = fmaf(w, (float)v.x, acc.x); acc.y = fmaf(w, (float)v.y, acc.y);
        acc.z = fmaf(w, (float)v.z, acc.z); acc.w = fmaf(w, (float)v.w, acc.w);
        wsum += w;
    }
    float dc = dinv[c];
    half4v vc = x4[(size_t)c * vpr + lane];
    acc.x = fmaf(dc, (float)vc.x, acc.x); acc.y = fmaf(dc, (float)vc.y, acc.y);
    acc.z = fmaf(dc, (float)vc.z, acc.z); acc.w = fmaf(dc, (float)vc.w, acc.w);
    wsum += dc;
    acc.x *= dc; acc.y *= dc; acc.z *= dc; acc.w *= dc;
    ((float4*)xout)[(size_t)c * vpr + lane] = acc;
    if (sarr && lane == 0) sarr[c] = dc * wsum;   // s = rowsum of A_norm
}

// ---------------- layer-2 aggregation: fp16 gather (128 ch), fp32 out ----------------
// 1 wave per destination, lane = half2 (4 B), 4x edge unroll.
__global__ void agg2_f16(const _Float16* __restrict__ zh, const int* __restrict__ srcs,
                         const int* __restrict__ offsets, const float* __restrict__ dinv,
                         float* __restrict__ xout, int vpr, int n) {
    int gw   = blockIdx.x * (blockDim.x >> 6) + (threadIdx.x >> 6);
    int lane = threadIdx.x & 63;
    if (gw >= n) return;
    int c   = __builtin_amdgcn_readfirstlane(gw);
    int beg = __builtin_amdgcn_readfirstlane(offsets[c]);
    int end = __builtin_amdgcn_readfirstlane(offsets[c + 1]);
    const half2v* x2 = (const half2v*)zh;
    float2 acc = make_float2(0.f, 0.f);
    int i = beg;
    for (; i + 3 < end; i += 4) {
        int r0 = __builtin_amdgcn_readfirstlane(srcs[i + 0]);
        int r1 = __builtin_amdgcn_readfirstlane(srcs[i + 1]);
        int r2 = __builtin_amdgcn_readfirstlane(srcs[i + 2]);
        int r3 = __builtin_amdgcn_readfirstlane(srcs[i + 3]);
        float w0 = dinv[r0], w1 = dinv[r1], w2 = dinv[r2], w3 = dinv[r3];
        half2v v0 = x2[(size_t)r0 * vpr + lane];
        half2v v1 = x2[(size_t)r1 * vpr + lane];
        half2v v2 = x2[(size_t)r2 * vpr + lane];
        half2v v3 = x2[(size_t)r3 * vpr + lane];
        acc.x = fmaf(w0, (float)v0.x, acc.x); acc.y = fmaf(w0, (float)v0.y, acc.y);
        acc.x = fmaf(w1, (float)v1.x, acc.x); acc.y = fmaf(w1, (float)v1.y, acc.y);
        acc.x = fmaf(w2, (float)v2.x, acc.x); acc.y = fmaf(w2, (float)v2.y, acc.y);
        acc.x = fmaf(w3, (float)v3.x, acc.x); acc.y = fmaf(w3, (float)v3.y, acc.y);
    }
    for (; i < end; ++i) {
        int r   = __builtin_amdgcn_readfirstlane(srcs[i]);
        float w = dinv[r];
        half2v v = x2[(size_t)r * vpr + lane];
        acc.x = fmaf(w, (float)v.x, acc.x); acc.y = fmaf(w, (float)v.y, acc.y);
    }
    float dc = dinv[c];
    half2v vc = x2[(size_t)c * vpr + lane];
    acc.x = fmaf(dc, (float)vc.x, acc.x); acc.y = fmaf(dc, (float)vc.y, acc.y);
    acc.x *= dc; acc.y *= dc;
    ((float2*)xout)[(size_t)c * vpr + lane] = acc;
}

// ---------------- fp32 tiled GEMM: C = A@B + bias (opt s[row]*bias), opt ReLU ----------------
template<int BM, int BN, bool RELU, bool SBIAS, typename OUTT>
__global__ __launch_bounds__(256) void gemm_kernel(
        const float* __restrict__ A, const float* __restrict__ B,
        const float* __restrict__ bias, const float* __restrict__ sarr,
        OUTT* __restrict__ C, int M, int K, int N) {
    constexpr int BK = 16;
    constexpr int TM = BM / 16, TN = BN / 16;
    static_assert(BM % 16 == 0 && BN % 16 == 0, "tile");
    __shared__ float As[BK][BM + 4];   // transposed: As[k][m]
    __shared__ float Bs[BK][BN + 4];
    int tid = threadIdx.x;
    int ty = tid >> 4, tx = tid & 15;
    int m0 = blockIdx.x * BM, n0 = blockIdx.y * BN;
    float acc[TM][TN] = {};
    for (int k0 = 0; k0 < K; k0 += BK) {
        #pragma unroll
        for (int l = 0; l < BM * BK / 1024; ++l) {
            int idx = tid + l * 256;
            int m  = idx >> 2;
            int kq = idx & 3;
            int gm = m0 + m;
            float4 v = make_float4(0.f, 0.f, 0.f, 0.f);
            if (gm < M) v = *(const float4*)(A + (size_t)gm * K + k0 + kq * 4);
            As[kq * 4 + 0][m] = v.x;
            As[kq * 4 + 1][m] = v.y;
            As[kq * 4 + 2][m] = v.z;
            As[kq * 4 + 3][m] = v.w;
        }
        #pragma unroll
        for (int l = 0; l < BK * BN / 1024; ++l) {
            int idx = tid + l * 256;
            int kk = idx / (BN / 4);
            int nq = idx % (BN / 4);
            float4 v = *(const float4*)(B + (size_t)(k0 + kk) * N + n0 + nq * 4);
            *(float4*)(&Bs[kk][nq * 4]) = v;
        }
        __syncthreads();
        #pragma unroll
        for (int kk = 0; kk < BK; ++kk) {
            float a[TM], b[TN];
            #pragma unroll
            for (int i = 0; i < TM; ++i) a[i] = As[kk][ty * TM + i];
            #pragma unroll
            for (int j = 0; j < TN; ++j) b[j] = Bs[kk][tx * TN + j];
            #pragma unroll
            for (int i = 0; i < TM; ++i)
                #pragma unroll
                for (int j = 0; j < TN; ++j)
                    acc[i][j] = fmaf(a[i], b[j], acc[i][j]);
        }
        __syncthreads();
    }
    #pragma unroll
    for (int i = 0; i < TM; ++i) {
        int row = m0 + ty * TM + i;
        if (row >= M) continue;
        float sv = SBIAS ? sarr[row] : 0.f;
        #pragma unroll
        for (int j = 0; j < TN; ++j) {
            int colj = n0 + tx * TN + j;
            float v = acc[i][j] + (SBIAS ? sv * bias[colj] : bias[colj]);
            if (RELU) v = fmaxf(v, 0.f);
            C[(size_t)row * N + colj] = (OUTT)v;
        }
    }
}

extern "C" void kernel_launch(void* const* d_in, const int* in_sizes, int n_in,
                              void* d_out, int out_size, void* d_ws, size_t ws_size,
                              hipStream_t stream) {
    const float* x  = (const float*)d_in[0];
    const int*   ei = (const int*)d_in[1];
    const float* W1 = (const float*)d_in[2];
    const float* b1 = (const float*)d_in[3];
    const float* W2 = (const float*)d_in[4];
    const float* b2 = (const float*)d_in[5];

    const int hid  = in_sizes[3];             // 512
    const int outc = in_sizes[5];             // 128
    const int inc  = in_sizes[2] / hid;       // 256
    const int n    = in_sizes[0] / inc;       // 20000
    const int E    = in_sizes[1] / 2;         // 640000
    const int* rowi = ei;                     // edge_index[0] = sources
    const int* coli = ei + E;                 // edge_index[1] = destinations

    char* p = (char*)d_ws;
    auto carve = [&](size_t bytes) {
        char* q = p;
        p += (bytes + 255) & ~(size_t)255;
        return (void*)q;
    };
    int*      counts  = (int*)     carve((size_t)n * 4);
    int*      offsets = (int*)     carve((size_t)(n + 1) * 4);
    int*      nexta   = (int*)     carve((size_t)n * 4);
    int*      srcs    = (int*)     carve((size_t)E * 4);
    float*    dinv    = (float*)   carve((size_t)n * 4);
    float*    sarr    = (float*)   carve((size_t)n * 4);
    int*      bsum    = (int*)     carve((size_t)32 * 4);
    _Float16* xh      = (_Float16*)carve((size_t)n * inc * 2);   // fp16 x table (also reused as zh)
    float*    aggx    = (float*)   carve((size_t)n * inc * 4);
    float*    h       = (float*)   carve((size_t)n * hid * 4);
    _Float16* zh      = xh;                                       // alias: xh dead after agg1

    const int SCAN_B = CDIV(n, 1024);

    zero_kernel<<<CDIV(n, 256), 256, 0, stream>>>(counts, n);
    hist_kernel<<<CDIV(E, 256), 256, 0, stream>>>(coli, counts, E);
    scan_part<<<SCAN_B, 1024, 0, stream>>>(counts, offsets, bsum, dinv, n);
    scan_fix<<<SCAN_B, 1024, 0, stream>>>(counts, offsets, bsum, nexta, n);
    scatter_kernel<<<CDIV(E, 256), 256, 0, stream>>>(rowi, coli, nexta, srcs, E);

    // layer 1: h = relu((A@x) @ W1 + s*b1), gather from fp16 x
    tohalf_kernel<<<CDIV(n * inc / 4, 256), 256, 0, stream>>>(x, xh, n * inc / 4);
    agg1_f16<<<CDIV(n, 4), 256, 0, stream>>>(xh, srcs, offsets, dinv, aggx, sarr, inc / 4, n);
    dim3 g1(CDIV(n, 128), hid / 128);
    gemm_kernel<128, 128, true, true, float><<<g1, 256, 0, stream>>>(aggx, W1, b1, sarr, h, n, inc, hid);

    // layer 2: out = A@(h @ W2 + b2), z stored fp16
    dim3 g2(CDIV(n, 64), outc / 128);
    gemm_kernel<64, 128, false, false, _Float16><<<g2, 256, 0, stream>>>(h, W2, b2, nullptr, zh, n, hid, outc);
    agg2_f16<<<CDIV(n, 4), 256, 0, stream>>>(zh, srcs, offsets, dinv, (float*)d_out, outc / 2, n);
}

// Round 6
// 236.201 us; speedup vs baseline: 1.5776x; 1.2656x over previous
//
#include <hip/hip_runtime.h>

#define CDIV(a,b) (((a)+(b)-1)/(b))

typedef _Float16 half4v __attribute__((ext_vector_type(4)));
typedef _Float16 half2v __attribute__((ext_vector_type(2)));
typedef _Float16 f16x8  __attribute__((ext_vector_type(8)));
typedef unsigned short ushort8v __attribute__((ext_vector_type(8)));
typedef float f32x4 __attribute__((ext_vector_type(4)));

// ---------------- zero int buffer (graph-capture-safe memset) ----------------
__global__ void zero_kernel(int* __restrict__ p, int n) {
    int i = blockIdx.x * blockDim.x + threadIdx.x;
    if (i < n) p[i] = 0;
}

// ---------------- degree histogram ----------------
__global__ void hist_kernel(const int* __restrict__ coli, int* __restrict__ counts, int E) {
    int e = blockIdx.x * blockDim.x + threadIdx.x;
    if (e < E) atomicAdd(&counts[coli[e]], 1);
}

// ---------------- hierarchical scan: part 1 (block-local inclusive) ----------------
__global__ __launch_bounds__(1024) void scan_part(const int* __restrict__ counts,
                                                  int* __restrict__ offsets,
                                                  int* __restrict__ bsum,
                                                  float* __restrict__ dinv, int n) {
    __shared__ int wsum[16];
    int b = blockIdx.x, tid = threadIdx.x;
    int i = b * 1024 + tid;
    int lane = tid & 63, wid = tid >> 6;
    int v = (i < n) ? counts[i] : 0;
    if (i < n) dinv[i] = 1.0f / sqrtf((float)(v + 1));   // self-loop => deg >= 1
    int x = v;
    #pragma unroll
    for (int off = 1; off < 64; off <<= 1) {
        int t = __shfl_up(x, off);
        if (lane >= off) x += t;
    }
    if (lane == 63) wsum[wid] = x;
    __syncthreads();
    if (tid == 0) {
        int run = 0;
        #pragma unroll
        for (int w = 0; w < 16; ++w) { int t = wsum[w]; wsum[w] = run; run += t; }
        bsum[b] = run;
    }
    __syncthreads();
    int incl = wsum[wid] + x;           // block-local inclusive prefix
    if (i < n) offsets[i + 1] = incl;
}

// ---------------- hierarchical scan: part 2 (add block prefix, emit nexta) ----------------
__global__ __launch_bounds__(1024) void scan_fix(const int* __restrict__ counts,
                                                 int* __restrict__ offsets,
                                                 const int* __restrict__ bsum,
                                                 int* __restrict__ nexta, int n) {
    int b = blockIdx.x, tid = threadIdx.x;
    int i = b * 1024 + tid;
    int pre = 0;
    for (int j = 0; j < b; ++j) pre += bsum[j];   // <=19 uniform loads
    if (i == 0) offsets[0] = 0;
    if (i < n) {
        int incl = offsets[i + 1] + pre;
        offsets[i + 1] = incl;
        nexta[i] = incl - counts[i];              // exclusive prefix = scatter cursor
    }
}

// ---------------- counting-sort scatter (build CSR src lists) ----------------
__global__ void scatter_kernel(const int* __restrict__ rowi, const int* __restrict__ coli,
                               int* __restrict__ nexta, int* __restrict__ srcs, int E) {
    int e = blockIdx.x * blockDim.x + threadIdx.x;
    if (e < E) {
        int c = coli[e];
        int pos = atomicAdd(&nexta[c], 1);
        srcs[pos] = rowi[e];
    }
}

// ---------------- fp32 -> fp16 table conversion ----------------
__global__ void tohalf_kernel(const float* __restrict__ in, _Float16* __restrict__ out, int n4) {
    int i = blockIdx.x * blockDim.x + threadIdx.x;
    if (i < n4) {
        float4 v = ((const float4*)in)[i];
        half4v h;
        h.x = (_Float16)v.x; h.y = (_Float16)v.y;
        h.z = (_Float16)v.z; h.w = (_Float16)v.w;
        ((half4v*)out)[i] = h;
    }
}

// ---------------- fp32 W (K x N) -> fp16 W^T (N x K), write-coalesced ----------------
__global__ void wt_kernel(const float* __restrict__ W, _Float16* __restrict__ WT, int K, int N) {
    int idx = blockIdx.x * blockDim.x + threadIdx.x;
    if (idx < K * N) {
        int nrow = idx / K, k = idx - nrow * K;
        WT[idx] = (_Float16)W[(size_t)k * N + nrow];
    }
}

// ---------------- layer-1 aggregation: fp16 gather (256 ch), fp32 accum, fp16 out ----------------
__global__ void agg1_f16(const _Float16* __restrict__ xh, const int* __restrict__ srcs,
                         const int* __restrict__ offsets, const float* __restrict__ dinv,
                         _Float16* __restrict__ xout, float* __restrict__ sarr,
                         int vpr, int n) {
    int gw   = blockIdx.x * (blockDim.x >> 6) + (threadIdx.x >> 6);
    int lane = threadIdx.x & 63;
    if (gw >= n) return;
    int c   = __builtin_amdgcn_readfirstlane(gw);
    int beg = __builtin_amdgcn_readfirstlane(offsets[c]);
    int end = __builtin_amdgcn_readfirstlane(offsets[c + 1]);
    const half4v* x4 = (const half4v*)xh;
    float4 acc = make_float4(0.f, 0.f, 0.f, 0.f);
    float wsum = 0.f;
    int i = beg;
    for (; i + 3 < end; i += 4) {
        int r0 = __builtin_amdgcn_readfirstlane(srcs[i + 0]);
        int r1 = __builtin_amdgcn_readfirstlane(srcs[i + 1]);
        int r2 = __builtin_amdgcn_readfirstlane(srcs[i + 2]);
        int r3 = __builtin_amdgcn_readfirstlane(srcs[i + 3]);
        float w0 = dinv[r0], w1 = dinv[r1], w2 = dinv[r2], w3 = dinv[r3];
        half4v v0 = x4[(size_t)r0 * vpr + lane];
        half4v v1 = x4[(size_t)r1 * vpr + lane];
        half4v v2 = x4[(size_t)r2 * vpr + lane];
        half4v v3 = x4[(size_t)r3 * vpr + lane];
        acc.x = fmaf(w0, (float)v0.x, acc.x); acc.y = fmaf(w0, (float)v0.y, acc.y);
        acc.z = fmaf(w0, (float)v0.z, acc.z); acc.w = fmaf(w0, (float)v0.w, acc.w);
        acc.x = fmaf(w1, (float)v1.x, acc.x); acc.y = fmaf(w1, (float)v1.y, acc.y);
        acc.z = fmaf(w1, (float)v1.z, acc.z); acc.w = fmaf(w1, (float)v1.w, acc.w);
        acc.x = fmaf(w2, (float)v2.x, acc.x); acc.y = fmaf(w2, (float)v2.y, acc.y);
        acc.z = fmaf(w2, (float)v2.z, acc.z); acc.w = fmaf(w2, (float)v2.w, acc.w);
        acc.x = fmaf(w3, (float)v3.x, acc.x); acc.y = fmaf(w3, (float)v3.y, acc.y);
        acc.z = fmaf(w3, (float)v3.z, acc.z); acc.w = fmaf(w3, (float)v3.w, acc.w);
        wsum += w0 + w1 + w2 + w3;
    }
    for (; i < end; ++i) {
        int r   = __builtin_amdgcn_readfirstlane(srcs[i]);
        float w = dinv[r];
        half4v v = x4[(size_t)r * vpr + lane];
        acc.x = fmaf(w, (float)v.x, acc.x); acc.y = fmaf(w, (float)v.y, acc.y);
        acc.z = fmaf(w, (float)v.z, acc.z); acc.w = fmaf(w, (float)v.w, acc.w);
        wsum += w;
    }
    float dc = dinv[c];
    half4v vc = x4[(size_t)c * vpr + lane];
    acc.x = fmaf(dc, (float)vc.x, acc.x); acc.y = fmaf(dc, (float)vc.y, acc.y);
    acc.z = fmaf(dc, (float)vc.z, acc.z); acc.w = fmaf(dc, (float)vc.w, acc.w);
    wsum += dc;
    half4v o;
    o.x = (_Float16)(acc.x * dc); o.y = (_Float16)(acc.y * dc);
    o.z = (_Float16)(acc.z * dc); o.w = (_Float16)(acc.w * dc);
    ((half4v*)xout)[(size_t)c * vpr + lane] = o;
    if (sarr && lane == 0) sarr[c] = dc * wsum;   // s = rowsum of A_norm
}

// ---------------- layer-2 aggregation: fp16 gather (128 ch), fp32 out ----------------
__global__ void agg2_f16(const _Float16* __restrict__ zh, const int* __restrict__ srcs,
                         const int* __restrict__ offsets, const float* __restrict__ dinv,
                         float* __restrict__ xout, int vpr, int n) {
    int gw   = blockIdx.x * (blockDim.x >> 6) + (threadIdx.x >> 6);
    int lane = threadIdx.x & 63;
    if (gw >= n) return;
    int c   = __builtin_amdgcn_readfirstlane(gw);
    int beg = __builtin_amdgcn_readfirstlane(offsets[c]);
    int end = __builtin_amdgcn_readfirstlane(offsets[c + 1]);
    const half2v* x2 = (const half2v*)zh;
    float2 acc = make_float2(0.f, 0.f);
    int i = beg;
    for (; i + 3 < end; i += 4) {
        int r0 = __builtin_amdgcn_readfirstlane(srcs[i + 0]);
        int r1 = __builtin_amdgcn_readfirstlane(srcs[i + 1]);
        int r2 = __builtin_amdgcn_readfirstlane(srcs[i + 2]);
        int r3 = __builtin_amdgcn_readfirstlane(srcs[i + 3]);
        float w0 = dinv[r0], w1 = dinv[r1], w2 = dinv[r2], w3 = dinv[r3];
        half2v v0 = x2[(size_t)r0 * vpr + lane];
        half2v v1 = x2[(size_t)r1 * vpr + lane];
        half2v v2 = x2[(size_t)r2 * vpr + lane];
        half2v v3 = x2[(size_t)r3 * vpr + lane];
        acc.x = fmaf(w0, (float)v0.x, acc.x); acc.y = fmaf(w0, (float)v0.y, acc.y);
        acc.x = fmaf(w1, (float)v1.x, acc.x); acc.y = fmaf(w1, (float)v1.y, acc.y);
        acc.x = fmaf(w2, (float)v2.x, acc.x); acc.y = fmaf(w2, (float)v2.y, acc.y);
        acc.x = fmaf(w3, (float)v3.x, acc.x); acc.y = fmaf(w3, (float)v3.y, acc.y);
    }
    for (; i < end; ++i) {
        int r   = __builtin_amdgcn_readfirstlane(srcs[i]);
        float w = dinv[r];
        half2v v = x2[(size_t)r * vpr + lane];
        acc.x = fmaf(w, (float)v.x, acc.x); acc.y = fmaf(w, (float)v.y, acc.y);
    }
    float dc = dinv[c];
    half2v vc = x2[(size_t)c * vpr + lane];
    acc.x = fmaf(dc, (float)vc.x, acc.x); acc.y = fmaf(dc, (float)vc.y, acc.y);
    acc.x *= dc; acc.y *= dc;
    ((float2*)xout)[(size_t)c * vpr + lane] = acc;
}

// ---------------- fp16 MFMA GEMM: C = A@B (+ bias or s*bias) (+relu), fp16 out ----------------
// A: MxK f16 row-major.  BT: NxK f16 row-major (B transposed).  C: MxN f16.
// 256 threads = 4 waves in 2x2 grid; wave tile (BM/2)x(BN/2); 16x16x32 MFMA.
// LDS rows padded 64B->80B: ds_read_b128 bank offset (r*20+q*4)%32 -> 2-way aliasing (free, m136).
template<int BM, int BN, bool RELU, bool SBIAS>
__global__ __launch_bounds__(256) void gemm_mfma(
        const _Float16* __restrict__ A, const _Float16* __restrict__ BT,
        const float* __restrict__ bias, const float* __restrict__ sarr,
        _Float16* __restrict__ C, int M, int K, int N) {
    constexpr int FM = BM / 2 / 16, FN = BN / 2 / 16;
    constexpr int APT = BM * 4 / 256, BPT = BN * 4 / 256;   // 16B granules per thread
    static_assert(BM % 32 == 0 && BN % 32 == 0, "wave tile divisibility");
    static_assert(BM * 4 % 256 == 0 && BN * 4 % 256 == 0, "staging divisibility");
    __shared__ unsigned short A_lds[BM * 40];   // 40 ushort = 80 B per 32-half row
    __shared__ unsigned short B_lds[BN * 40];
    int tid  = threadIdx.x;
    int wid  = tid >> 6, lane = tid & 63;
    int wm   = wid >> 1, wn = wid & 1;
    int q    = lane >> 4, r = lane & 15;
    int m0   = blockIdx.x * BM, n0 = blockIdx.y * BN;

    f32x4 acc[FM][FN];
    #pragma unroll
    for (int i = 0; i < FM; ++i)
        #pragma unroll
        for (int j = 0; j < FN; ++j)
            acc[i][j] = (f32x4){0.f, 0.f, 0.f, 0.f};

    ushort8v areg[APT], breg[BPT];
    auto loadA = [&](int k0) {
        #pragma unroll
        for (int i = 0; i < APT; ++i) {
            int g = tid + i * 256;
            int row = g >> 2, slot = g & 3;
            int gm = m0 + row;
            if (gm < M) areg[i] = *(const ushort8v*)(A + (size_t)gm * K + k0 + slot * 8);
            else        areg[i] = (ushort8v){0,0,0,0,0,0,0,0};
        }
    };
    auto loadB = [&](int k0) {
        #pragma unroll
        for (int i = 0; i < BPT; ++i) {
            int g = tid + i * 256;
            int row = g >> 2, slot = g & 3;
            breg[i] = *(const ushort8v*)(BT + (size_t)(n0 + row) * K + k0 + slot * 8);
        }
    };

    loadA(0); loadB(0);
    int steps = K / 32;
    for (int s = 0; s < steps; ++s) {
        __syncthreads();                      // prev compute done reading LDS
        #pragma unroll
        for (int i = 0; i < APT; ++i) {
            int g = tid + i * 256;
            *(ushort8v*)&A_lds[(g >> 2) * 40 + (g & 3) * 8] = areg[i];
        }
        #pragma unroll
        for (int i = 0; i < BPT; ++i) {
            int g = tid + i * 256;
            *(ushort8v*)&B_lds[(g >> 2) * 40 + (g & 3) * 8] = breg[i];
        }
        __syncthreads();                      // LDS ready
        if (s + 1 < steps) { loadA((s + 1) * 32); loadB((s + 1) * 32); }  // overlap w/ MFMA
        f16x8 af[FM], bf[FN];
        #pragma unroll
        for (int i = 0; i < FM; ++i)
            af[i] = *(const f16x8*)&A_lds[(wm * (BM / 2) + i * 16 + r) * 40 + q * 8];
        #pragma unroll
        for (int j = 0; j < FN; ++j)
            bf[j] = *(const f16x8*)&B_lds[(wn * (BN / 2) + j * 16 + r) * 40 + q * 8];
        #pragma unroll
        for (int i = 0; i < FM; ++i)
            #pragma unroll
            for (int j = 0; j < FN; ++j)
                acc[i][j] = __builtin_amdgcn_mfma_f32_16x16x32_f16(af[i], bf[j], acc[i][j], 0, 0, 0);
    }

    // epilogue: D row = q*4+reg, col = r  (m89-verified layout)
    #pragma unroll
    for (int i = 0; i < FM; ++i) {
        int row_base = m0 + wm * (BM / 2) + i * 16 + q * 4;
        #pragma unroll
        for (int g = 0; g < 4; ++g) {
            int row = row_base + g;
            if (row >= M) continue;
            float sv = SBIAS ? sarr[row] : 1.f;
            #pragma unroll
            for (int j = 0; j < FN; ++j) {
                int col = n0 + wn * (BN / 2) + j * 16 + r;
                float v = acc[i][j][g] + sv * bias[col];
                if (RELU) v = fmaxf(v, 0.f);
                C[(size_t)row * N + col] = (_Float16)v;
            }
        }
    }
}

extern "C" void kernel_launch(void* const* d_in, const int* in_sizes, int n_in,
                              void* d_out, int out_size, void* d_ws, size_t ws_size,
                              hipStream_t stream) {
    const float* x  = (const float*)d_in[0];
    const int*   ei = (const int*)d_in[1];
    const float* W1 = (const float*)d_in[2];
    const float* b1 = (const float*)d_in[3];
    const float* W2 = (const float*)d_in[4];
    const float* b2 = (const float*)d_in[5];

    const int hid  = in_sizes[3];             // 512
    const int outc = in_sizes[5];             // 128
    const int inc  = in_sizes[2] / hid;       // 256
    const int n    = in_sizes[0] / inc;       // 20000
    const int E    = in_sizes[1] / 2;         // 640000
    const int* rowi = ei;                     // edge_index[0] = sources
    const int* coli = ei + E;                 // edge_index[1] = destinations

    char* p = (char*)d_ws;
    auto carve = [&](size_t bytes) {
        char* q = p;
        p += (bytes + 255) & ~(size_t)255;
        return (void*)q;
    };
    int*      counts  = (int*)     carve((size_t)n * 4);
    int*      offsets = (int*)     carve((size_t)(n + 1) * 4);
    int*      nexta   = (int*)     carve((size_t)n * 4);
    int*      srcs    = (int*)     carve((size_t)E * 4);
    float*    dinv    = (float*)   carve((size_t)n * 4);
    float*    sarr    = (float*)   carve((size_t)n * 4);
    int*      bsum    = (int*)     carve((size_t)32 * 4);
    _Float16* xh      = (_Float16*)carve((size_t)n * inc * 2);   // fp16 x (reused as zh)
    _Float16* aggxh   = (_Float16*)carve((size_t)n * inc * 2);   // fp16 A@x
    _Float16* hh      = (_Float16*)carve((size_t)n * hid * 2);   // fp16 hidden
    _Float16* w1t     = (_Float16*)carve((size_t)inc * hid * 2); // fp16 W1^T [hid][inc]
    _Float16* w2t     = (_Float16*)carve((size_t)hid * outc * 2);// fp16 W2^T [outc][hid]
    _Float16* zh      = xh;                                       // alias: xh dead after agg1

    const int SCAN_B = CDIV(n, 1024);

    zero_kernel<<<CDIV(n, 256), 256, 0, stream>>>(counts, n);
    hist_kernel<<<CDIV(E, 256), 256, 0, stream>>>(coli, counts, E);
    scan_part<<<SCAN_B, 1024, 0, stream>>>(counts, offsets, bsum, dinv, n);
    scan_fix<<<SCAN_B, 1024, 0, stream>>>(counts, offsets, bsum, nexta, n);
    scatter_kernel<<<CDIV(E, 256), 256, 0, stream>>>(rowi, coli, nexta, srcs, E);

    // weight prep (fp16 transposed)
    wt_kernel<<<CDIV(inc * hid, 256), 256, 0, stream>>>(W1, w1t, inc, hid);
    wt_kernel<<<CDIV(hid * outc, 256), 256, 0, stream>>>(W2, w2t, hid, outc);

    // layer 1: h = relu((A@x) @ W1 + s*b1)
    tohalf_kernel<<<CDIV(n * inc / 4, 256), 256, 0, stream>>>(x, xh, n * inc / 4);
    agg1_f16<<<CDIV(n, 4), 256, 0, stream>>>(xh, srcs, offsets, dinv, aggxh, sarr, inc / 4, n);
    dim3 g1(CDIV(n, 128), hid / 128);
    gemm_mfma<128, 128, true, true><<<g1, 256, 0, stream>>>(aggxh, w1t, b1, sarr, hh, n, inc, hid);

    // layer 2: out = A@(h @ W2 + b2)
    dim3 g2(CDIV(n, 64), outc / 128);
    gemm_mfma<64, 128, false, false><<<g2, 256, 0, stream>>>(hh, w2t, b2, nullptr, zh, n, hid, outc);
    agg2_f16<<<CDIV(n, 4), 256, 0, stream>>>(zh, srcs, offsets, dinv, (float*)d_out, outc / 2, n);
}